// Round 6
// baseline (70.229 us; speedup 1.0000x reference)
//
#include <hip/hip_runtime.h>

#define CSC 2.88539008177792681f  // 2*log2(e)

typedef float v2f __attribute__((ext_vector_type(2)));

__device__ __forceinline__ float fast_exp2(float x) {
  return __builtin_amdgcn_exp2f(x);
}
__device__ __forceinline__ float fast_rcp(float x) {
  return __builtin_amdgcn_rcpf(x);
}
__device__ __forceinline__ v2f vfma(v2f a, v2f b, v2f c) {
  return __builtin_elementwise_fma(a, b, c);
}
__device__ __forceinline__ v2f vsplat(float s) {
  v2f r;
  r[0] = s;
  r[1] = s;
  return r;
}

// ---------------- projection (unchanged) ----------------
__global__ __launch_bounds__(256) void proj_kernel(
    const float* __restrict__ query, const float* __restrict__ key,
    const float* __restrict__ weight, float* __restrict__ Eq,
    float* __restrict__ EkT) {
  __shared__ __align__(16) float rows[16][128];
  __shared__ __align__(16) float tile[16][128];
  int blk = blockIdx.x;
  bool isK = blk >= 128;
  const float* src = isK ? key : query;
  int woff = isK ? 128 : 0;
  int row0 = (isK ? blk - 128 : blk) * 16;
  int tid = threadIdx.x;
#pragma unroll
  for (int i = 0; i < 8; ++i) {
    int f = i * 256 + tid;
    rows[f >> 7][f & 127] = src[(size_t)row0 * 128 + f];
  }
  __syncthreads();
  int e = tid & 127;
  int rh = (tid >> 7) * 8;  // wave-uniform
  float acc[8];
#pragma unroll
  for (int i = 0; i < 8; ++i) acc[i] = 0.f;
  const float4* wrow =
      reinterpret_cast<const float4*>(weight + (size_t)e * 256 + woff);
#pragma unroll 4
  for (int d4 = 0; d4 < 32; ++d4) {
    float4 wv = wrow[d4];
#pragma unroll
    for (int i = 0; i < 8; ++i) {
      float4 rv = *reinterpret_cast<const float4*>(&rows[rh + i][d4 * 4]);
      acc[i] = fmaf(rv.x, wv.x, acc[i]);
      acc[i] = fmaf(rv.y, wv.y, acc[i]);
      acc[i] = fmaf(rv.z, wv.z, acc[i]);
      acc[i] = fmaf(rv.w, wv.w, acc[i]);
    }
  }
  if (!isK) {
#pragma unroll
    for (int i = 0; i < 8; ++i)
      Eq[(size_t)(row0 + rh + i) * 128 + e] = fast_exp2(CSC * acc[i]);
  } else {
#pragma unroll
    for (int i = 0; i < 8; ++i) tile[rh + i][e] = fast_exp2(CSC * acc[i]);
    __syncthreads();
    int eo = tid >> 1;
    int rseg = (tid & 1) * 8;
    float4 v0 = make_float4(tile[rseg + 0][eo], tile[rseg + 1][eo],
                            tile[rseg + 2][eo], tile[rseg + 3][eo]);
    float4 v1 = make_float4(tile[rseg + 4][eo], tile[rseg + 5][eo],
                            tile[rseg + 6][eo], tile[rseg + 7][eo]);
    float* dst = EkT + (size_t)eo * 2048 + row0 + rseg;
    *reinterpret_cast<float4*>(dst) = v0;
    *reinterpret_cast<float4*>(dst + 4) = v1;
  }
}

// 4-way reciprocal combine over an e-quad, v2f-wide over 2 k.
// sum_e vT_e/(1+eq_e*ek_e) = num/den; all A>=1, den<=2^98, f32-safe.
__device__ __forceinline__ void quad4(const float4 eq, const float4 vt, v2f ek0,
                                      v2f ek1, v2f ek2, v2f ek3, v2f& acc) {
  v2f one = vsplat(1.f);
  v2f A0 = vfma(vsplat(eq.x), ek0, one);
  v2f A1 = vfma(vsplat(eq.y), ek1, one);
  v2f A2 = vfma(vsplat(eq.z), ek2, one);
  v2f A3 = vfma(vsplat(eq.w), ek3, one);
  v2f P01 = A0 * A1;
  v2f P23 = A2 * A3;
  v2f t01 = vfma(vsplat(vt.x), A1, vsplat(vt.y) * A0);
  v2f t23 = vfma(vsplat(vt.z), A3, vsplat(vt.w) * A2);
  v2f num = vfma(t23, P01, t01 * P23);
  v2f den = P01 * P23;
  v2f r;
  r[0] = fast_rcp(den[0]);
  r[1] = fast_rcp(den[1]);
  acc = vfma(num, r, acc);
}

// Attention partial: grid 1024 = 2(b) x 128(qg) x 4(kh); 512 threads (8 waves).
// Block = 8 q-rows x 256-k slice. Thread = 2 q x 2 k. Writes UNNORMALIZED
// PV partial (pblk[bi][8][128]) + per-half-wave exp-sum partials (dsum[bi][16]).
// LDS exactly 40 KB -> up to 4 blocks/CU.
__global__ __launch_bounds__(512, 4) void attn_kernel(
    const float* __restrict__ Eq, const float* __restrict__ EkT,
    const float* __restrict__ vT, const float* __restrict__ value,
    float* __restrict__ pblk, float* __restrict__ dsum) {
  __shared__ __align__(16) float sc[8][256];    // 8 KB: p values
  __shared__ __align__(16) v2f pout[8][8][64];  // 32 KB: per-wave PV partials

  int tid = threadIdx.x;
  int lane = tid & 63;
  int w = tid >> 6;
  int bi = blockIdx.x;
  int b = bi >> 9;
  int qg = (bi >> 2) & 127;
  int kh = bi & 3;
  int q0 = qg * 8;
  int koff = kh * 256;
  int kp = tid & 127;  // k-pair within slice (k = 2kp, 2kp+1)
  int qp = tid >> 7;   // q-pair index 0..3 (wave-uniform: w>>1)

  // ---- scores + exp + row partial sums ----
  {
    const float* ekp = EkT + (size_t)b * 1024 + koff + 2 * kp;
    const float* eqb = Eq + (size_t)(b * 1024 + q0 + qp * 2) * 128;
    v2f accA = vsplat(0.f), accB = vsplat(0.f);
#pragma unroll 2
    for (int e = 0; e < 128; e += 4) {
      v2f ek0 = *reinterpret_cast<const v2f*>(ekp + (size_t)(e + 0) * 2048);
      v2f ek1 = *reinterpret_cast<const v2f*>(ekp + (size_t)(e + 1) * 2048);
      v2f ek2 = *reinterpret_cast<const v2f*>(ekp + (size_t)(e + 2) * 2048);
      v2f ek3 = *reinterpret_cast<const v2f*>(ekp + (size_t)(e + 3) * 2048);
      float4 vt4 = *reinterpret_cast<const float4*>(vT + e);   // block-uniform
      float4 eqA = *reinterpret_cast<const float4*>(eqb + e);  // wave-uniform
      float4 eqB = *reinterpret_cast<const float4*>(eqb + 128 + e);
      quad4(eqA, vt4, ek0, ek1, ek2, ek3, accA);
      quad4(eqB, vt4, ek0, ek1, ek2, ek3, accB);
    }
    v2f pA, pB;
    pA[0] = fast_exp2(-CSC * accA[0]);
    pA[1] = fast_exp2(-CSC * accA[1]);
    pB[0] = fast_exp2(-CSC * accB[0]);
    pB[1] = fast_exp2(-CSC * accB[1]);
    *reinterpret_cast<v2f*>(&sc[qp * 2 + 0][2 * kp]) = pA;
    *reinterpret_cast<v2f*>(&sc[qp * 2 + 1][2 * kp]) = pB;
    float sA = pA[0] + pA[1];
    float sB = pB[0] + pB[1];
#pragma unroll
    for (int off = 32; off; off >>= 1) {
      sA += __shfl_xor(sA, off);
      sB += __shfl_xor(sB, off);
    }
    if (lane == 0) {
      dsum[(size_t)bi * 16 + (qp * 2 + 0) * 2 + (w & 1)] = sA;
      dsum[(size_t)bi * 16 + (qp * 2 + 1) * 2 + (w & 1)] = sB;
    }
  }
  __syncthreads();

  // ---- PV partial: wave w -> local k in [w*32, w*32+32), all 8 q;
  //      lane -> v2f column; p broadcast via ds_read_b128 ----
  {
    v2f acc[8];
#pragma unroll
    for (int q = 0; q < 8; ++q) acc[q] = vsplat(0.f);
    int kb = w * 32;
    const v2f* vp = reinterpret_cast<const v2f*>(value) +
                    ((size_t)b * 1024 + koff + kb) * 64 + lane;
#pragma unroll 2
    for (int k4 = 0; k4 < 8; ++k4) {
      v2f vv0 = vp[(size_t)(k4 * 4 + 0) * 64];
      v2f vv1 = vp[(size_t)(k4 * 4 + 1) * 64];
      v2f vv2 = vp[(size_t)(k4 * 4 + 2) * 64];
      v2f vv3 = vp[(size_t)(k4 * 4 + 3) * 64];
#pragma unroll
      for (int q = 0; q < 8; ++q) {
        float4 pp = *reinterpret_cast<const float4*>(&sc[q][kb + k4 * 4]);
        acc[q] = vfma(vsplat(pp.x), vv0, acc[q]);
        acc[q] = vfma(vsplat(pp.y), vv1, acc[q]);
        acc[q] = vfma(vsplat(pp.z), vv2, acc[q]);
        acc[q] = vfma(vsplat(pp.w), vv3, acc[q]);
      }
    }
#pragma unroll
    for (int q = 0; q < 8; ++q) pout[w][q][lane] = acc[q];
  }
  __syncthreads();

  // ---- cross-wave reduce -> workspace (unnormalized) ----
  {
    int q = tid >> 6;
    v2f r = pout[0][q][lane];
#pragma unroll
    for (int ww = 1; ww < 8; ++ww) r = r + pout[ww][q][lane];
    *reinterpret_cast<v2f*>(pblk + (size_t)bi * 1024 + q * 128 + 2 * lane) = r;
  }
}

// Combine: sum 4 k-slice partials, normalize. 256 blocks x 512 threads,
// thread -> one (row, v2f col) of out[2048][128].
__global__ __launch_bounds__(512) void combine_kernel(
    const float* __restrict__ pblk, const float* __restrict__ dsum,
    float* __restrict__ out) {
  int g = blockIdx.x * 512 + threadIdx.x;
  int row = g >> 6;  // wave-uniform
  int c = g & 63;
  int b = row >> 10;
  int qg = (row >> 3) & 127;
  int q = row & 7;
  int bi0 = b * 512 + qg * 4;
  v2f r = vsplat(0.f);
  float d = 0.f;
#pragma unroll
  for (int kh = 0; kh < 4; ++kh) {
    r = r + *reinterpret_cast<const v2f*>(
                pblk + (size_t)(bi0 + kh) * 1024 + q * 128 + 2 * c);
    d += dsum[(size_t)(bi0 + kh) * 16 + q * 2 + 0] +
         dsum[(size_t)(bi0 + kh) * 16 + q * 2 + 1];
  }
  float inv = fast_rcp(d);
  r[0] *= inv;
  r[1] *= inv;
  *reinterpret_cast<v2f*>(out + (size_t)row * 128 + 2 * c) = r;
}

extern "C" void kernel_launch(void* const* d_in, const int* in_sizes, int n_in,
                              void* d_out, int out_size, void* d_ws,
                              size_t ws_size, hipStream_t stream) {
  const float* query = (const float*)d_in[0];
  const float* key = (const float*)d_in[1];
  const float* value = (const float*)d_in[2];
  const float* vT = (const float*)d_in[3];
  const float* weight = (const float*)d_in[4];
  float* out = (float*)d_out;
  float* Eq = (float*)d_ws;          // 2048*128 f32 = 1 MB
  float* EkT = Eq + 262144;          // 128 x 2048 f32 = 1 MB (transposed)
  float* pblk = EkT + 262144;        // 1024 x 8 x 128 f32 = 4 MB
  float* dsum = pblk + 1048576;      // 1024 x 16 f32 = 64 KB
  proj_kernel<<<256, 256, 0, stream>>>(query, key, weight, Eq, EkT);
  attn_kernel<<<1024, 512, 0, stream>>>(Eq, EkT, vT, value, pblk, dsum);
  combine_kernel<<<256, 512, 0, stream>>>(pblk, dsum, out);
}

// Round 7
// 50.282 us; speedup vs baseline: 1.3967x; 1.3967x over previous
//
#include <hip/hip_runtime.h>

#define CSC 2.88539008177792681f  // 2*log2(e)

typedef float v2f __attribute__((ext_vector_type(2)));

__device__ __forceinline__ float fast_exp2(float x) {
  return __builtin_amdgcn_exp2f(x);
}
__device__ __forceinline__ float fast_rcp(float x) {
  return __builtin_amdgcn_rcpf(x);
}
__device__ __forceinline__ v2f vfma(v2f a, v2f b, v2f c) {
  return __builtin_elementwise_fma(a, b, c);
}
__device__ __forceinline__ v2f vsplat(float s) {
  v2f r;
  r[0] = s;
  r[1] = s;
  return r;
}

// Projection: 256 blocks x 256 threads. Blocks 0..127 -> Eq row-major
// [qrow][e]; 128..255 -> EkT4 interleaved-transposed [e/4][col][4] so the
// attention score loop reads one float4 (4 e-values for its k) per e-quad,
// fully coalesced over k.
__global__ __launch_bounds__(256) void proj_kernel(
    const float* __restrict__ query, const float* __restrict__ key,
    const float* __restrict__ weight, float* __restrict__ Eq,
    float* __restrict__ EkT4) {
  __shared__ __align__(16) float rows[16][128];
  __shared__ __align__(16) float tile[16][132];  // +4 pad: conflict-free reads
  int blk = blockIdx.x;
  bool isK = blk >= 128;
  const float* src = isK ? key : query;
  int woff = isK ? 128 : 0;
  int row0 = (isK ? blk - 128 : blk) * 16;
  int tid = threadIdx.x;
#pragma unroll
  for (int i = 0; i < 8; ++i) {
    int f = i * 256 + tid;
    rows[f >> 7][f & 127] = src[(size_t)row0 * 128 + f];
  }
  __syncthreads();
  int e = tid & 127;
  int rh = (tid >> 7) * 8;  // wave-uniform
  float acc[8];
#pragma unroll
  for (int i = 0; i < 8; ++i) acc[i] = 0.f;
  const float4* wrow =
      reinterpret_cast<const float4*>(weight + (size_t)e * 256 + woff);
#pragma unroll 4
  for (int d4 = 0; d4 < 32; ++d4) {
    float4 wv = wrow[d4];
#pragma unroll
    for (int i = 0; i < 8; ++i) {
      float4 rv = *reinterpret_cast<const float4*>(&rows[rh + i][d4 * 4]);
      acc[i] = fmaf(rv.x, wv.x, acc[i]);
      acc[i] = fmaf(rv.y, wv.y, acc[i]);
      acc[i] = fmaf(rv.z, wv.z, acc[i]);
      acc[i] = fmaf(rv.w, wv.w, acc[i]);
    }
  }
  if (!isK) {
#pragma unroll
    for (int i = 0; i < 8; ++i)
      Eq[(size_t)(row0 + rh + i) * 128 + e] = fast_exp2(CSC * acc[i]);
  } else {
#pragma unroll
    for (int i = 0; i < 8; ++i) tile[rh + i][e] = fast_exp2(CSC * acc[i]);
    __syncthreads();
    int kk = tid & 15;
    int e4a = tid >> 4;  // 0..15
#pragma unroll
    for (int h = 0; h < 2; ++h) {
      int ee = e4a + h * 16;  // e-quad index 0..31
      float4 v = *reinterpret_cast<const float4*>(&tile[kk][ee * 4]);
      *reinterpret_cast<float4*>(EkT4 + ((size_t)ee * 2048 + row0 + kk) * 4) =
          v;
    }
  }
}

// Attention: grid 256 (b = blk>>7, q0 = (blk&127)*8), 1024 threads (16 waves).
// Thread = 8 q-rows x 1 k (k = tid) x 128 e. eq/vT block-uniform -> s_load.
// EkT4/value each read exactly once per block. PV: wave w -> k-chunk
// [w*64,+64) x all 8 q, p broadcast via ds_read_b128; fused 16-way reduce.
// score' = -2*sum_e vT_e/(1+Eq*Ek); sum(vT) cancels in softmax; scores
// bounded (|.|<=~18) so no max subtraction.
__global__ __launch_bounds__(1024, 4) void attn_kernel(
    const float* __restrict__ Eq, const float* __restrict__ EkT4,
    const float* __restrict__ vT, const float* __restrict__ value,
    float* __restrict__ out) {
  __shared__ __align__(16) float sc[8][1024];      // 32 KB p-values
  __shared__ __align__(16) float pout[16][8][128]; // 64 KB PV partials
  __shared__ float wsum[16][8];
  __shared__ float denom[8];

  int tid = threadIdx.x;
  int lane = tid & 63;
  int w = tid >> 6;
  int b = blockIdx.x >> 7;
  int q0 = (blockIdx.x & 127) * 8;

  // ---- scores + exp + row partial sums ----
  {
    const float4* ekp =
        reinterpret_cast<const float4*>(EkT4) + (size_t)b * 1024 + tid;
    const float* eqb = Eq + (size_t)(b * 1024 + q0) * 128;  // block-uniform
    const float4* vtp = reinterpret_cast<const float4*>(vT);
    float acc[8];
#pragma unroll
    for (int q = 0; q < 8; ++q) acc[q] = 0.f;
    for (int e4 = 0; e4 < 32; ++e4) {
      float4 ek = ekp[(size_t)e4 * 2048];
      float4 vt4 = vtp[e4];  // uniform -> SMEM
#pragma unroll
      for (int q = 0; q < 8; ++q) {
        float4 eqq = *reinterpret_cast<const float4*>(
            eqb + (size_t)q * 128 + e4 * 4);  // uniform -> SMEM
        float A0 = fmaf(eqq.x, ek.x, 1.f);
        float A1 = fmaf(eqq.y, ek.y, 1.f);
        float A2 = fmaf(eqq.z, ek.z, 1.f);
        float A3 = fmaf(eqq.w, ek.w, 1.f);
        float P01 = A0 * A1;
        float P23 = A2 * A3;
        float t01 = fmaf(vt4.x, A1, vt4.y * A0);
        float t23 = fmaf(vt4.z, A3, vt4.w * A2);
        float num = fmaf(t23, P01, t01 * P23);
        acc[q] = fmaf(num, fast_rcp(P01 * P23), acc[q]);
      }
    }
#pragma unroll
    for (int q = 0; q < 8; ++q) {
      float p = fast_exp2(-CSC * acc[q]);
      sc[q][tid] = p;
      float s = p;
#pragma unroll
      for (int off = 32; off; off >>= 1) s += __shfl_xor(s, off);
      if (lane == 0) wsum[w][q] = s;
    }
  }
  __syncthreads();
  if (tid < 8) {
    float s = 0.f;
#pragma unroll
    for (int ww = 0; ww < 16; ++ww) s += wsum[ww][tid];
    denom[tid] = s;
  }

  // ---- PV: wave w -> k in [w*64, w*64+64), all 8 q; lane -> v2f column ----
  {
    int kb = w * 64;
    v2f acc2[8];
#pragma unroll
    for (int q = 0; q < 8; ++q) acc2[q] = vsplat(0.f);
    const v2f* vp = reinterpret_cast<const v2f*>(value) +
                    ((size_t)b * 1024 + kb) * 64 + lane;
#pragma unroll 2
    for (int k4 = 0; k4 < 16; ++k4) {
      v2f vv0 = vp[(size_t)(k4 * 4 + 0) * 64];
      v2f vv1 = vp[(size_t)(k4 * 4 + 1) * 64];
      v2f vv2 = vp[(size_t)(k4 * 4 + 2) * 64];
      v2f vv3 = vp[(size_t)(k4 * 4 + 3) * 64];
#pragma unroll
      for (int q = 0; q < 8; ++q) {
        float4 pp = *reinterpret_cast<const float4*>(&sc[q][kb + k4 * 4]);
        acc2[q] = vfma(vsplat(pp.x), vv0, acc2[q]);
        acc2[q] = vfma(vsplat(pp.y), vv1, acc2[q]);
        acc2[q] = vfma(vsplat(pp.z), vv2, acc2[q]);
        acc2[q] = vfma(vsplat(pp.w), vv3, acc2[q]);
      }
    }
#pragma unroll
    for (int q = 0; q < 8; ++q)
      *reinterpret_cast<v2f*>(&pout[w][q][2 * lane]) = acc2[q];
  }
  __syncthreads();

  // ---- 16-way reduce + normalize: thread -> (q = tid>>7, c = tid&127) ----
  {
    int q = tid >> 7;
    int c = tid & 127;
    float r = 0.f;
#pragma unroll
    for (int ww = 0; ww < 16; ++ww) r += pout[ww][q][c];
    r *= fast_rcp(denom[q]);
    out[((size_t)b * 1024 + q0 + q) * 128 + c] = r;
  }
}

extern "C" void kernel_launch(void* const* d_in, const int* in_sizes, int n_in,
                              void* d_out, int out_size, void* d_ws,
                              size_t ws_size, hipStream_t stream) {
  const float* query = (const float*)d_in[0];
  const float* key = (const float*)d_in[1];
  const float* value = (const float*)d_in[2];
  const float* vT = (const float*)d_in[3];
  const float* weight = (const float*)d_in[4];
  float* out = (float*)d_out;
  float* Eq = (float*)d_ws;       // 2048*128 f32 = 1 MB (row-major [row][e])
  float* EkT4 = Eq + 262144;      // 32 x 2048 x 4 f32 = 1 MB (interleaved-T)
  proj_kernel<<<256, 256, 0, stream>>>(query, key, weight, Eq, EkT4);
  attn_kernel<<<256, 1024, 0, stream>>>(Eq, EkT4, vT, value, out);
}

// Round 8
// 48.551 us; speedup vs baseline: 1.4465x; 1.0357x over previous
//
#include <hip/hip_runtime.h>

#define CSC 2.88539008177792681f  // 2*log2(e)

typedef float v2f __attribute__((ext_vector_type(2)));

__device__ __forceinline__ float fast_exp2(float x) {
  return __builtin_amdgcn_exp2f(x);
}
__device__ __forceinline__ float fast_rcp(float x) {
  return __builtin_amdgcn_rcpf(x);
}
__device__ __forceinline__ v2f vfma(v2f a, v2f b, v2f c) {
  return __builtin_elementwise_fma(a, b, c);
}
__device__ __forceinline__ v2f vsplat(float s) {
  v2f r;
  r[0] = s;
  r[1] = s;
  return r;
}

// Projection: 256 blocks x 256 threads. Blocks 0..127 -> Eq row-major
// [qrow][e]; 128..255 -> EkT4 interleaved-transposed [e/4][col][4] so the
// attention score loop reads one float4 (4 e-values for its k) per e-quad,
// fully coalesced over k.
__global__ __launch_bounds__(256) void proj_kernel(
    const float* __restrict__ query, const float* __restrict__ key,
    const float* __restrict__ weight, float* __restrict__ Eq,
    float* __restrict__ EkT4) {
  __shared__ __align__(16) float rows[16][128];
  __shared__ __align__(16) float tile[16][132];  // +4 pad: conflict-free reads
  int blk = blockIdx.x;
  bool isK = blk >= 128;
  const float* src = isK ? key : query;
  int woff = isK ? 128 : 0;
  int row0 = (isK ? blk - 128 : blk) * 16;
  int tid = threadIdx.x;
#pragma unroll
  for (int i = 0; i < 8; ++i) {
    int f = i * 256 + tid;
    rows[f >> 7][f & 127] = src[(size_t)row0 * 128 + f];
  }
  __syncthreads();
  int e = tid & 127;
  int rh = (tid >> 7) * 8;  // wave-uniform
  float acc[8];
#pragma unroll
  for (int i = 0; i < 8; ++i) acc[i] = 0.f;
  const float4* wrow =
      reinterpret_cast<const float4*>(weight + (size_t)e * 256 + woff);
#pragma unroll 4
  for (int d4 = 0; d4 < 32; ++d4) {
    float4 wv = wrow[d4];
#pragma unroll
    for (int i = 0; i < 8; ++i) {
      float4 rv = *reinterpret_cast<const float4*>(&rows[rh + i][d4 * 4]);
      acc[i] = fmaf(rv.x, wv.x, acc[i]);
      acc[i] = fmaf(rv.y, wv.y, acc[i]);
      acc[i] = fmaf(rv.z, wv.z, acc[i]);
      acc[i] = fmaf(rv.w, wv.w, acc[i]);
    }
  }
  if (!isK) {
#pragma unroll
    for (int i = 0; i < 8; ++i)
      Eq[(size_t)(row0 + rh + i) * 128 + e] = fast_exp2(CSC * acc[i]);
  } else {
#pragma unroll
    for (int i = 0; i < 8; ++i) tile[rh + i][e] = fast_exp2(CSC * acc[i]);
    __syncthreads();
    int kk = tid & 15;
    int e4a = tid >> 4;  // 0..15
#pragma unroll
    for (int h = 0; h < 2; ++h) {
      int ee = e4a + h * 16;  // e-quad index 0..31
      float4 v = *reinterpret_cast<const float4*>(&tile[kk][ee * 4]);
      *reinterpret_cast<float4*>(EkT4 + ((size_t)ee * 2048 + row0 + kk) * 4) =
          v;
    }
  }
}

// Attention partial: grid 512 = b(2) x qg(128) x kh(2); 512 threads (8 waves).
// Block = 8 q-rows x 512-k slice; thread = 8 q x 1 k x 128 e (same per-thread
// work/loads as R7, but 2 blocks/CU -> two independent barrier domains).
// eq/vT block-uniform -> s_load. Writes UNNORMALIZED PV partials + exp-sums.
// score' = -2*sum_e vT_e/(1+Eq*Ek); sum(vT) cancels; scores bounded -> no max.
__global__ __launch_bounds__(512, 4) void attn_kernel(
    const float* __restrict__ Eq, const float* __restrict__ EkT4,
    const float* __restrict__ vT, const float* __restrict__ value,
    float* __restrict__ pblk, float* __restrict__ dsum) {
  __shared__ __align__(16) float sc[8][512];    // 16 KB p-values
  __shared__ __align__(16) v2f pout[8][8][64];  // 32 KB PV partials
  __shared__ float wsum[8][8];

  int tid = threadIdx.x;
  int lane = tid & 63;
  int w = tid >> 6;
  int bi = blockIdx.x;
  int kh = bi & 1;
  int qg = (bi >> 1) & 127;
  int b = bi >> 8;
  int q0 = qg * 8;
  int k0 = kh * 512;

  // ---- scores + exp + row partial sums ----
  {
    const float4* ekp = reinterpret_cast<const float4*>(EkT4) +
                        (size_t)b * 1024 + k0 + tid;
    const float* eqb = Eq + (size_t)(b * 1024 + q0) * 128;  // block-uniform
    const float4* vtp = reinterpret_cast<const float4*>(vT);
    float acc[8];
#pragma unroll
    for (int q = 0; q < 8; ++q) acc[q] = 0.f;
#pragma unroll 2
    for (int e4 = 0; e4 < 32; ++e4) {
      float4 ek = ekp[(size_t)e4 * 2048];
      float4 vt4 = vtp[e4];  // uniform -> SMEM
#pragma unroll
      for (int q = 0; q < 8; ++q) {
        float4 eqq = *reinterpret_cast<const float4*>(
            eqb + (size_t)q * 128 + e4 * 4);  // uniform -> SMEM
        float A0 = fmaf(eqq.x, ek.x, 1.f);
        float A1 = fmaf(eqq.y, ek.y, 1.f);
        float A2 = fmaf(eqq.z, ek.z, 1.f);
        float A3 = fmaf(eqq.w, ek.w, 1.f);
        float P01 = A0 * A1;
        float P23 = A2 * A3;
        float t01 = fmaf(vt4.x, A1, vt4.y * A0);
        float t23 = fmaf(vt4.z, A3, vt4.w * A2);
        float num = fmaf(t23, P01, t01 * P23);
        acc[q] = fmaf(num, fast_rcp(P01 * P23), acc[q]);
      }
    }
#pragma unroll
    for (int q = 0; q < 8; ++q) {
      float p = fast_exp2(-CSC * acc[q]);
      sc[q][tid] = p;
      float s = p;
#pragma unroll
      for (int off = 32; off; off >>= 1) s += __shfl_xor(s, off);
      if (lane == 0) wsum[w][q] = s;
    }
  }
  __syncthreads();
  if (tid < 8) {
    float s = 0.f;
#pragma unroll
    for (int ww = 0; ww < 8; ++ww) s += wsum[ww][tid];
    dsum[(size_t)bi * 8 + tid] = s;
  }

  // ---- PV partial: wave w -> local k in [w*64,+64), all 8 q;
  //      lane -> v2f column; p broadcast via ds_read_b128 ----
  {
    int kb = w * 64;
    v2f acc2[8];
#pragma unroll
    for (int q = 0; q < 8; ++q) acc2[q] = vsplat(0.f);
    const v2f* vp = reinterpret_cast<const v2f*>(value) +
                    ((size_t)b * 1024 + k0 + kb) * 64 + lane;
#pragma unroll 2
    for (int k4 = 0; k4 < 16; ++k4) {
      v2f vv0 = vp[(size_t)(k4 * 4 + 0) * 64];
      v2f vv1 = vp[(size_t)(k4 * 4 + 1) * 64];
      v2f vv2 = vp[(size_t)(k4 * 4 + 2) * 64];
      v2f vv3 = vp[(size_t)(k4 * 4 + 3) * 64];
#pragma unroll
      for (int q = 0; q < 8; ++q) {
        float4 pp = *reinterpret_cast<const float4*>(&sc[q][kb + k4 * 4]);
        acc2[q] = vfma(vsplat(pp.x), vv0, acc2[q]);
        acc2[q] = vfma(vsplat(pp.y), vv1, acc2[q]);
        acc2[q] = vfma(vsplat(pp.z), vv2, acc2[q]);
        acc2[q] = vfma(vsplat(pp.w), vv3, acc2[q]);
      }
    }
#pragma unroll
    for (int q = 0; q < 8; ++q) pout[w][q][lane] = acc2[q];
  }
  __syncthreads();

  // ---- 8-way cross-wave reduce -> workspace (unnormalized) ----
  {
    int q = tid >> 6;
    int c = tid & 63;
    v2f r = pout[0][q][c];
#pragma unroll
    for (int ww = 1; ww < 8; ++ww) r = r + pout[ww][q][c];
    *reinterpret_cast<v2f*>(pblk + (size_t)bi * 1024 + q * 128 + 2 * c) = r;
  }
}

// Combine: sum the 2 k-half partials, normalize. 256 blocks x 512 threads;
// thread -> one (row, v2f col) of out[2048][128].
__global__ __launch_bounds__(512) void combine_kernel(
    const float* __restrict__ pblk, const float* __restrict__ dsum,
    float* __restrict__ out) {
  int g = blockIdx.x * 512 + threadIdx.x;
  int row = g >> 6;
  int c = g & 63;
  int b = row >> 10;
  int qg = (row >> 3) & 127;
  int q = row & 7;
  int bi0 = b * 256 + qg * 2;
  v2f r0 = *reinterpret_cast<const v2f*>(pblk + (size_t)bi0 * 1024 + q * 128 +
                                         2 * c);
  v2f r1 = *reinterpret_cast<const v2f*>(pblk + (size_t)(bi0 + 1) * 1024 +
                                         q * 128 + 2 * c);
  float d = dsum[(size_t)bi0 * 8 + q] + dsum[(size_t)(bi0 + 1) * 8 + q];
  v2f r = r0 + r1;
  float inv = fast_rcp(d);
  r[0] *= inv;
  r[1] *= inv;
  *reinterpret_cast<v2f*>(out + (size_t)row * 128 + 2 * c) = r;
}

extern "C" void kernel_launch(void* const* d_in, const int* in_sizes, int n_in,
                              void* d_out, int out_size, void* d_ws,
                              size_t ws_size, hipStream_t stream) {
  const float* query = (const float*)d_in[0];
  const float* key = (const float*)d_in[1];
  const float* value = (const float*)d_in[2];
  const float* vT = (const float*)d_in[3];
  const float* weight = (const float*)d_in[4];
  float* out = (float*)d_out;
  float* Eq = (float*)d_ws;      // 2048*128 f32 = 1 MB
  float* EkT4 = Eq + 262144;     // 32 x 2048 x 4 f32 = 1 MB (interleaved-T)
  float* pblk = EkT4 + 262144;   // 512 x 8 x 128 f32 = 2 MB
  float* dsum = pblk + 524288;   // 512 x 8 f32 = 16 KB
  proj_kernel<<<256, 256, 0, stream>>>(query, key, weight, Eq, EkT4);
  attn_kernel<<<512, 512, 0, stream>>>(Eq, EkT4, vT, value, pblk, dsum);
  combine_kernel<<<256, 512, 0, stream>>>(pblk, dsum, out);
}